// Round 1
// baseline (210.501 us; speedup 1.0000x reference)
//
#include <hip/hip_runtime.h>

#define N_NODES 10000
#define D 128
#define N_EDGES 640000

// ---------------- CSR build ----------------

__global__ __launch_bounds__(256) void hist_kernel(const int* __restrict__ ei,
                                                   int* __restrict__ deg) {
    int i = blockIdx.x * 256 + threadIdx.x;
    if (i < N_EDGES) {
        int d = ei[N_EDGES + i];   // row 1 = dst
        atomicAdd(&deg[d], 1);
    }
}

// single-block exclusive scan over deg[0..N_NODES) -> row_start[0..N_NODES]
__global__ __launch_bounds__(1024) void scan_kernel(const int* __restrict__ deg,
                                                    int* __restrict__ row_start) {
    __shared__ int partial[1024];
    const int t = threadIdx.x;
    const int CH = 10;                 // 1024*10 = 10240 >= 10000
    int base = t * CH;
    int local[CH];
    int s = 0;
#pragma unroll
    for (int c = 0; c < CH; ++c) {
        int i = base + c;
        int v = (i < N_NODES) ? deg[i] : 0;
        local[c] = s;                  // exclusive within chunk
        s += v;
    }
    partial[t] = s;
    __syncthreads();
    // Hillis-Steele inclusive scan over 1024 partials
    for (int off = 1; off < 1024; off <<= 1) {
        int v = (t >= off) ? partial[t - off] : 0;
        __syncthreads();
        partial[t] += v;
        __syncthreads();
    }
    int prev = (t > 0) ? partial[t - 1] : 0;
#pragma unroll
    for (int c = 0; c < CH; ++c) {
        int i = base + c;
        if (i < N_NODES) row_start[i] = prev + local[c];
    }
    if (t == 1023) row_start[N_NODES] = partial[1023];   // = N_EDGES
}

__global__ __launch_bounds__(256) void scatter_kernel(const int* __restrict__ ei,
                                                      const int* __restrict__ row_start,
                                                      int* __restrict__ cursor,
                                                      int* __restrict__ csr) {
    int i = blockIdx.x * 256 + threadIdx.x;
    if (i < N_EDGES) {
        int s = ei[i];                 // row 0 = src
        int d = ei[N_EDGES + i];
        int pos = row_start[d] + atomicAdd(&cursor[d], 1);
        csr[pos] = s;
    }
}

// ---------------- mean aggregation (atomic-free) ----------------
// one block of 128 threads per dst node; thread f owns feature f

__global__ __launch_bounds__(128) void aggregate_kernel(const float* __restrict__ x,
                                                        const int* __restrict__ row_start,
                                                        const int* __restrict__ csr,
                                                        float* __restrict__ agg) {
    int node = blockIdx.x;
    int f = threadIdx.x;
    int start = row_start[node];
    int end = row_start[node + 1];
    float a0 = 0.f, a1 = 0.f, a2 = 0.f, a3 = 0.f;
    int e = start;
    for (; e + 3 < end; e += 4) {
        int s0 = csr[e], s1 = csr[e + 1], s2 = csr[e + 2], s3 = csr[e + 3];
        a0 += x[s0 * D + f];
        a1 += x[s1 * D + f];
        a2 += x[s2 * D + f];
        a3 += x[s3 * D + f];
    }
    for (; e < end; ++e) a0 += x[csr[e] * D + f];
    float sum = (a0 + a1) + (a2 + a3);
    int cnt = end - start;
    agg[node * D + f] = (cnt > 0) ? sum / (float)cnt : 0.0f;
}

// ---------------- SAGE linear + residual ----------------
// out[i][f] = x[i][f] + b_l[f] + sum_k agg[i][k]*W_l[f][k] + sum_k x[i][k]*W_r[f][k]
// 8 nodes per block of 128 threads; x/agg rows staged in LDS (broadcast reads)

__global__ __launch_bounds__(128) void lin_kernel(const float* __restrict__ x,
                                                  const float* __restrict__ agg,
                                                  const float* __restrict__ Wl,
                                                  const float* __restrict__ bl,
                                                  const float* __restrict__ Wr,
                                                  float* __restrict__ out) {
    __shared__ float4 xs[8][32];
    __shared__ float4 as[8][32];
    float* xsf = (float*)xs;
    float* asf = (float*)as;
    const int f = threadIdx.x;
    const int n0 = blockIdx.x * 8;

    for (int n = 0; n < 8; ++n) {
        xsf[n * D + f] = x[(n0 + n) * D + f];
        asf[n * D + f] = agg[(n0 + n) * D + f];
    }
    __syncthreads();

    float bias = bl[f];
    float acc[8];
#pragma unroll
    for (int n = 0; n < 8; ++n) acc[n] = bias;

    const float4* wl4 = (const float4*)(Wl + f * D);
    const float4* wr4 = (const float4*)(Wr + f * D);
    for (int kk = 0; kk < 32; ++kk) {
        float4 wl = wl4[kk];
        float4 wr = wr4[kk];
#pragma unroll
        for (int n = 0; n < 8; ++n) {
            float4 a = as[n][kk];
            float4 xv = xs[n][kk];
            acc[n] += a.x * wl.x + a.y * wl.y + a.z * wl.z + a.w * wl.w;
            acc[n] += xv.x * wr.x + xv.y * wr.y + xv.z * wr.z + xv.w * wr.w;
        }
    }

    for (int n = 0; n < 8; ++n) {
        out[(n0 + n) * D + f] = xsf[n * D + f] + acc[n];
    }
}

extern "C" void kernel_launch(void* const* d_in, const int* in_sizes, int n_in,
                              void* d_out, int out_size, void* d_ws, size_t ws_size,
                              hipStream_t stream) {
    const float* x  = (const float*)d_in[0];
    const int*   ei = (const int*)d_in[1];     // [2, E] int32
    const float* Wl = (const float*)d_in[2];   // [128,128]
    const float* bl = (const float*)d_in[3];   // [128]
    const float* Wr = (const float*)d_in[4];   // [128,128]
    float* out = (float*)d_out;

    // workspace layout (16B-aligned chunks)
    int* deg       = (int*)d_ws;               // 10000 (pad to 10016)
    int* cursor    = deg + 10016;              // 10000 (pad to 10016)
    int* row_start = cursor + 10016;           // 10001 (pad to 10016)
    int* csr       = row_start + 10016;        // 640000
    float* agg     = (float*)(csr + N_EDGES);  // 1,280,000 floats

    // zero deg + cursor (adjacent)
    hipMemsetAsync(deg, 0, (size_t)2 * 10016 * sizeof(int), stream);

    hist_kernel<<<(N_EDGES + 255) / 256, 256, 0, stream>>>(ei, deg);
    scan_kernel<<<1, 1024, 0, stream>>>(deg, row_start);
    scatter_kernel<<<(N_EDGES + 255) / 256, 256, 0, stream>>>(ei, row_start, cursor, csr);
    aggregate_kernel<<<N_NODES, 128, 0, stream>>>(x, row_start, csr, agg);
    lin_kernel<<<N_NODES / 8, 128, 0, stream>>>(x, agg, Wl, bl, Wr, out);
}

// Round 2
// 185.248 us; speedup vs baseline: 1.1363x; 1.1363x over previous
//
#include <hip/hip_runtime.h>

#define N_NODES 10000
#define D 128
#define N_EDGES 640000

// ---------------- CSR build ----------------
// Pass 1: histogram AND per-edge rank in one atomic pass.
// atomicAdd returns the old value = this edge's rank within its dst bucket.

__global__ __launch_bounds__(256) void hist_rank_kernel(const int* __restrict__ ei,
                                                        int* __restrict__ deg,
                                                        int* __restrict__ rank) {
    int i = blockIdx.x * 256 + threadIdx.x;
    if (i < N_EDGES) {
        int d = ei[N_EDGES + i];   // row 1 = dst
        rank[i] = atomicAdd(&deg[d], 1);
    }
}

// single-block exclusive scan over deg[0..N_NODES) -> row_start[0..N_NODES]
__global__ __launch_bounds__(1024) void scan_kernel(const int* __restrict__ deg,
                                                    int* __restrict__ row_start) {
    __shared__ int partial[1024];
    const int t = threadIdx.x;
    const int CH = 10;                 // 1024*10 = 10240 >= 10000
    int base = t * CH;
    int local[CH];
    int s = 0;
#pragma unroll
    for (int c = 0; c < CH; ++c) {
        int i = base + c;
        int v = (i < N_NODES) ? deg[i] : 0;
        local[c] = s;                  // exclusive within chunk
        s += v;
    }
    partial[t] = s;
    __syncthreads();
    for (int off = 1; off < 1024; off <<= 1) {
        int v = (t >= off) ? partial[t - off] : 0;
        __syncthreads();
        partial[t] += v;
        __syncthreads();
    }
    int prev = (t > 0) ? partial[t - 1] : 0;
#pragma unroll
    for (int c = 0; c < CH; ++c) {
        int i = base + c;
        if (i < N_NODES) row_start[i] = prev + local[c];
    }
    if (t == 1023) row_start[N_NODES] = partial[1023];   // = N_EDGES
}

// Pass 2: atomic-free scatter using the precomputed rank.
__global__ __launch_bounds__(256) void scatter_kernel(const int* __restrict__ ei,
                                                      const int* __restrict__ row_start,
                                                      const int* __restrict__ rank,
                                                      int* __restrict__ csr) {
    int i = blockIdx.x * 256 + threadIdx.x;
    if (i < N_EDGES) {
        int s = ei[i];                 // row 0 = src
        int d = ei[N_EDGES + i];
        csr[row_start[d] + rank[i]] = s;
    }
}

// ---------------- mean aggregation (atomic-free, float4 gather) ----------------
// one block of 128 threads per dst node: 4 edge-slots x 32 lanes x float4.

__global__ __launch_bounds__(128) void aggregate_kernel(const float4* __restrict__ x4,
                                                        const int* __restrict__ row_start,
                                                        const int* __restrict__ csr,
                                                        float4* __restrict__ agg4) {
    __shared__ float4 red[4][32];
    const int node = blockIdx.x;
    const int lane = threadIdx.x & 31;   // feature group: 4*lane .. 4*lane+3
    const int slot = threadIdx.x >> 5;   // edge slot 0..3
    const int start = row_start[node];
    const int end = row_start[node + 1];

    float4 acc = make_float4(0.f, 0.f, 0.f, 0.f);
    for (int e = start + slot; e < end; e += 4) {
        int s = csr[e];
        float4 v = x4[s * 32 + lane];
        acc.x += v.x; acc.y += v.y; acc.z += v.z; acc.w += v.w;
    }
    red[slot][lane] = acc;
    __syncthreads();
    if (slot == 0) {
        float4 a = red[0][lane];
        float4 b = red[1][lane];
        float4 c = red[2][lane];
        float4 d = red[3][lane];
        int cnt = end - start;
        float inv = (cnt > 0) ? 1.0f / (float)cnt : 0.0f;
        float4 o;
        o.x = ((a.x + b.x) + (c.x + d.x)) * inv;
        o.y = ((a.y + b.y) + (c.y + d.y)) * inv;
        o.z = ((a.z + b.z) + (c.z + d.z)) * inv;
        o.w = ((a.w + b.w) + (c.w + d.w)) * inv;
        agg4[node * 32 + lane] = o;
    }
}

// ---------------- SAGE linear + residual ----------------
// out[i][f] = x[i][f] + b_l[f] + sum_k agg[i][k]*W_l[f][k] + sum_k x[i][k]*W_r[f][k]

__global__ __launch_bounds__(128) void lin_kernel(const float* __restrict__ x,
                                                  const float* __restrict__ agg,
                                                  const float* __restrict__ Wl,
                                                  const float* __restrict__ bl,
                                                  const float* __restrict__ Wr,
                                                  float* __restrict__ out) {
    __shared__ float4 xs[8][32];
    __shared__ float4 as[8][32];
    float* xsf = (float*)xs;
    float* asf = (float*)as;
    const int f = threadIdx.x;
    const int n0 = blockIdx.x * 8;

    for (int n = 0; n < 8; ++n) {
        xsf[n * D + f] = x[(n0 + n) * D + f];
        asf[n * D + f] = agg[(n0 + n) * D + f];
    }
    __syncthreads();

    float bias = bl[f];
    float acc[8];
#pragma unroll
    for (int n = 0; n < 8; ++n) acc[n] = bias;

    const float4* wl4 = (const float4*)(Wl + f * D);
    const float4* wr4 = (const float4*)(Wr + f * D);
    for (int kk = 0; kk < 32; ++kk) {
        float4 wl = wl4[kk];
        float4 wr = wr4[kk];
#pragma unroll
        for (int n = 0; n < 8; ++n) {
            float4 a = as[n][kk];
            float4 xv = xs[n][kk];
            acc[n] += a.x * wl.x + a.y * wl.y + a.z * wl.z + a.w * wl.w;
            acc[n] += xv.x * wr.x + xv.y * wr.y + xv.z * wr.z + xv.w * wr.w;
        }
    }

    for (int n = 0; n < 8; ++n) {
        out[(n0 + n) * D + f] = xsf[n * D + f] + acc[n];
    }
}

extern "C" void kernel_launch(void* const* d_in, const int* in_sizes, int n_in,
                              void* d_out, int out_size, void* d_ws, size_t ws_size,
                              hipStream_t stream) {
    const float* x  = (const float*)d_in[0];
    const int*   ei = (const int*)d_in[1];     // [2, E] int32
    const float* Wl = (const float*)d_in[2];   // [128,128]
    const float* bl = (const float*)d_in[3];   // [128]
    const float* Wr = (const float*)d_in[4];   // [128,128]
    float* out = (float*)d_out;

    // workspace layout (all 16B-aligned)
    int* deg       = (int*)d_ws;               // 10016
    int* row_start = deg + 10016;              // 10016 (holds 10001)
    int* rank      = row_start + 10016;        // 640000
    int* csr       = rank + N_EDGES;           // 640000
    float* agg     = (float*)(csr + N_EDGES);  // 1,280,000 floats

    hipMemsetAsync(deg, 0, (size_t)10016 * sizeof(int), stream);

    hist_rank_kernel<<<(N_EDGES + 255) / 256, 256, 0, stream>>>(ei, deg, rank);
    scan_kernel<<<1, 1024, 0, stream>>>(deg, row_start);
    scatter_kernel<<<(N_EDGES + 255) / 256, 256, 0, stream>>>(ei, row_start, rank, csr);
    aggregate_kernel<<<N_NODES, 128, 0, stream>>>((const float4*)x, row_start, csr,
                                                  (float4*)agg);
    lin_kernel<<<N_NODES / 8, 128, 0, stream>>>(x, agg, Wl, bl, Wr, out);
}

// Round 3
// 158.278 us; speedup vs baseline: 1.3299x; 1.1704x over previous
//
#include <hip/hip_runtime.h>

#define N_NODES 10000
#define D 128
#define N_EDGES 640000
#define NB 128                 // histogram blocks
#define EPB (N_EDGES / NB)     // 5000 edges per block

// ---------------- CSR build: two-level LDS counting sort ----------------

// A: per-block LDS histogram + local rank (LDS atomics, no global contention)
__global__ __launch_bounds__(1024) void hist_local_kernel(const int* __restrict__ ei,
                                                          int* __restrict__ lrank,
                                                          int* __restrict__ cnt) {
    __shared__ int h[N_NODES];
    for (int n = threadIdx.x; n < N_NODES; n += 1024) h[n] = 0;
    __syncthreads();
    const int base = blockIdx.x * EPB;
    for (int e = base + threadIdx.x; e < base + EPB; e += 1024) {
        int d = ei[N_EDGES + e];            // row 1 = dst
        lrank[e] = atomicAdd(&h[d], 1);
    }
    __syncthreads();
    int* c = cnt + blockIdx.x * N_NODES;
    for (int n = threadIdx.x; n < N_NODES; n += 1024) c[n] = h[n];
}

// B: per-node exclusive scan across the NB blocks (coalesced), emit deg
__global__ __launch_bounds__(256) void colscan_kernel(int* __restrict__ cnt,
                                                      int* __restrict__ deg) {
    int n = blockIdx.x * 256 + threadIdx.x;
    if (n < N_NODES) {
        int s = 0;
#pragma unroll 8
        for (int b = 0; b < NB; ++b) {
            int idx = b * N_NODES + n;
            int t = cnt[idx];
            cnt[idx] = s;
            s += t;
        }
        deg[n] = s;
    }
}

// C: single-block exclusive scan over deg[0..N_NODES) -> row_start[0..N_NODES]
__global__ __launch_bounds__(1024) void scan_kernel(const int* __restrict__ deg,
                                                    int* __restrict__ row_start) {
    __shared__ int partial[1024];
    const int t = threadIdx.x;
    const int CH = 10;                 // 1024*10 = 10240 >= 10000
    int base = t * CH;
    int local[CH];
    int s = 0;
#pragma unroll
    for (int c = 0; c < CH; ++c) {
        int i = base + c;
        int v = (i < N_NODES) ? deg[i] : 0;
        local[c] = s;
        s += v;
    }
    partial[t] = s;
    __syncthreads();
    for (int off = 1; off < 1024; off <<= 1) {
        int v = (t >= off) ? partial[t - off] : 0;
        __syncthreads();
        partial[t] += v;
        __syncthreads();
    }
    int prev = (t > 0) ? partial[t - 1] : 0;
#pragma unroll
    for (int c = 0; c < CH; ++c) {
        int i = base + c;
        if (i < N_NODES) row_start[i] = prev + local[c];
    }
    if (t == 1023) row_start[N_NODES] = partial[1023];
}

// D: fully atomic-free scatter
__global__ __launch_bounds__(256) void scatter_kernel(const int* __restrict__ ei,
                                                      const int* __restrict__ row_start,
                                                      const int* __restrict__ cnt,
                                                      const int* __restrict__ lrank,
                                                      int* __restrict__ csr) {
    int i = blockIdx.x * 256 + threadIdx.x;
    if (i < N_EDGES) {
        int b = i / EPB;
        int s = ei[i];
        int d = ei[N_EDGES + i];
        int pos = row_start[d] + cnt[b * N_NODES + d] + lrank[i];
        csr[pos] = s;
    }
}

// ---------------- mean aggregation (atomic-free, float4 gather) ----------------

__global__ __launch_bounds__(128) void aggregate_kernel(const float4* __restrict__ x4,
                                                        const int* __restrict__ row_start,
                                                        const int* __restrict__ csr,
                                                        float4* __restrict__ agg4) {
    __shared__ float4 red[4][32];
    const int node = blockIdx.x;
    const int lane = threadIdx.x & 31;
    const int slot = threadIdx.x >> 5;
    const int start = row_start[node];
    const int end = row_start[node + 1];

    float4 acc = make_float4(0.f, 0.f, 0.f, 0.f);
    for (int e = start + slot; e < end; e += 4) {
        int s = csr[e];
        float4 v = x4[s * 32 + lane];
        acc.x += v.x; acc.y += v.y; acc.z += v.z; acc.w += v.w;
    }
    red[slot][lane] = acc;
    __syncthreads();
    if (slot == 0) {
        float4 a = red[0][lane];
        float4 b = red[1][lane];
        float4 c = red[2][lane];
        float4 d = red[3][lane];
        int cnt = end - start;
        float inv = (cnt > 0) ? 1.0f / (float)cnt : 0.0f;
        float4 o;
        o.x = ((a.x + b.x) + (c.x + d.x)) * inv;
        o.y = ((a.y + b.y) + (c.y + d.y)) * inv;
        o.z = ((a.z + b.z) + (c.z + d.z)) * inv;
        o.w = ((a.w + b.w) + (c.w + d.w)) * inv;
        agg4[node * 32 + lane] = o;
    }
}

// ---------------- SAGE linear + residual ----------------

__global__ __launch_bounds__(128) void lin_kernel(const float* __restrict__ x,
                                                  const float* __restrict__ agg,
                                                  const float* __restrict__ Wl,
                                                  const float* __restrict__ bl,
                                                  const float* __restrict__ Wr,
                                                  float* __restrict__ out) {
    __shared__ float4 xs[8][32];
    __shared__ float4 as[8][32];
    float* xsf = (float*)xs;
    float* asf = (float*)as;
    const int f = threadIdx.x;
    const int n0 = blockIdx.x * 8;

    for (int n = 0; n < 8; ++n) {
        xsf[n * D + f] = x[(n0 + n) * D + f];
        asf[n * D + f] = agg[(n0 + n) * D + f];
    }
    __syncthreads();

    float bias = bl[f];
    float acc[8];
#pragma unroll
    for (int n = 0; n < 8; ++n) acc[n] = bias;

    const float4* wl4 = (const float4*)(Wl + f * D);
    const float4* wr4 = (const float4*)(Wr + f * D);
    for (int kk = 0; kk < 32; ++kk) {
        float4 wl = wl4[kk];
        float4 wr = wr4[kk];
#pragma unroll
        for (int n = 0; n < 8; ++n) {
            float4 a = as[n][kk];
            float4 xv = xs[n][kk];
            acc[n] += a.x * wl.x + a.y * wl.y + a.z * wl.z + a.w * wl.w;
            acc[n] += xv.x * wr.x + xv.y * wr.y + xv.z * wr.z + xv.w * wr.w;
        }
    }

    for (int n = 0; n < 8; ++n) {
        out[(n0 + n) * D + f] = xsf[n * D + f] + acc[n];
    }
}

extern "C" void kernel_launch(void* const* d_in, const int* in_sizes, int n_in,
                              void* d_out, int out_size, void* d_ws, size_t ws_size,
                              hipStream_t stream) {
    const float* x  = (const float*)d_in[0];
    const int*   ei = (const int*)d_in[1];     // [2, E] int32
    const float* Wl = (const float*)d_in[2];
    const float* bl = (const float*)d_in[3];
    const float* Wr = (const float*)d_in[4];
    float* out = (float*)d_out;

    // workspace layout (all 16B-aligned)
    int* deg       = (int*)d_ws;                 // 10016
    int* row_start = deg + 10016;                // 10016 (holds 10001)
    int* lrank     = row_start + 10016;          // 640000
    int* cnt       = lrank + N_EDGES;            // NB*N_NODES = 1,280,000
    int* csr       = cnt + NB * N_NODES;         // 640000
    float* agg     = (float*)(csr + N_EDGES);    // 1,280,000 floats

    hist_local_kernel<<<NB, 1024, 0, stream>>>(ei, lrank, cnt);
    colscan_kernel<<<(N_NODES + 255) / 256, 256, 0, stream>>>(cnt, deg);
    scan_kernel<<<1, 1024, 0, stream>>>(deg, row_start);
    scatter_kernel<<<(N_EDGES + 255) / 256, 256, 0, stream>>>(ei, row_start, cnt, lrank, csr);
    aggregate_kernel<<<N_NODES, 128, 0, stream>>>((const float4*)x, row_start, csr,
                                                  (float4*)agg);
    lin_kernel<<<N_NODES / 8, 128, 0, stream>>>(x, agg, Wl, bl, Wr, out);
}

// Round 4
// 144.086 us; speedup vs baseline: 1.4609x; 1.0985x over previous
//
#include <hip/hip_runtime.h>

#define N_NODES 10000
#define D 128
#define N_EDGES 640000
#define NB 128                 // histogram blocks
#define EPB (N_EDGES / NB)     // 5000 edges per block
#define SB 40                  // scan blocks
#define NPSB 250               // nodes per scan block

// ---------------- CSR build: two-level LDS counting sort ----------------

// A: per-block LDS histogram + local rank. Block 0 also zeroes the lookback flags.
__global__ __launch_bounds__(1024) void hist_local_kernel(const int* __restrict__ ei,
                                                          unsigned short* __restrict__ lrank,
                                                          unsigned short* __restrict__ cnt,
                                                          unsigned long long* __restrict__ flags) {
    __shared__ int h[N_NODES];
    for (int n = threadIdx.x; n < N_NODES; n += 1024) h[n] = 0;
    if (blockIdx.x == 0 && threadIdx.x < SB) flags[threadIdx.x] = 0ULL;
    __syncthreads();
    const int base = blockIdx.x * EPB;
    for (int e = base + threadIdx.x; e < base + EPB; e += 1024) {
        int d = ei[N_EDGES + e];            // row 1 = dst
        lrank[e] = (unsigned short)atomicAdd(&h[d], 1);
    }
    __syncthreads();
    unsigned short* c = cnt + (size_t)blockIdx.x * N_NODES;
    for (int n = threadIdx.x; n < N_NODES; n += 1024) c[n] = (unsigned short)h[n];
}

// B: fused per-node column scan + global node scan (decoupled lookback, 40 blocks).
__global__ __launch_bounds__(256) void colscan_scan_kernel(unsigned short* __restrict__ cnt,
                                                           int* __restrict__ row_start,
                                                           unsigned long long* __restrict__ flags) {
    const int t = threadIdx.x;
    const int b = blockIdx.x;
    const int n = b * NPSB + t;            // valid for t < NPSB
    __shared__ int sc[256];
    __shared__ int blk_excl_sh;

    int deg = 0;
    if (t < NPSB) {
        int s = 0;
#pragma unroll 8
        for (int j = 0; j < NB; ++j) {
            int idx = j * N_NODES + n;
            int v = cnt[idx];
            cnt[idx] = (unsigned short)s;  // exclusive prefix within column
            s += v;
        }
        deg = s;
    }
    sc[t] = deg;
    __syncthreads();
    // inclusive Hillis-Steele over 256
    for (int off = 1; off < 256; off <<= 1) {
        int v = (t >= off) ? sc[t - off] : 0;
        __syncthreads();
        sc[t] += v;
        __syncthreads();
    }
    const int total = sc[255];
    const int local_excl = sc[t] - deg;

    if (t == 0) {
        int excl = 0;
        if (b == 0) {
            __hip_atomic_store(&flags[0], (2ULL << 32) | (unsigned)total,
                               __ATOMIC_RELEASE, __HIP_MEMORY_SCOPE_AGENT);
        } else {
            __hip_atomic_store(&flags[b], (1ULL << 32) | (unsigned)total,
                               __ATOMIC_RELEASE, __HIP_MEMORY_SCOPE_AGENT);
            int j = b - 1;
            while (j >= 0) {
                unsigned long long f = __hip_atomic_load(&flags[j], __ATOMIC_ACQUIRE,
                                                         __HIP_MEMORY_SCOPE_AGENT);
                unsigned st = (unsigned)(f >> 32);
                if (st == 0) continue;           // spin: 40 blocks always co-resident
                excl += (int)(unsigned)(f & 0xffffffffULL);
                if (st == 2) break;
                --j;
            }
            __hip_atomic_store(&flags[b], (2ULL << 32) | (unsigned)(excl + total),
                               __ATOMIC_RELEASE, __HIP_MEMORY_SCOPE_AGENT);
        }
        blk_excl_sh = excl;
    }
    __syncthreads();
    if (t < NPSB) row_start[n] = blk_excl_sh + local_excl;
    if (b == SB - 1 && t == 0) row_start[N_NODES] = N_EDGES;
}

// C: fully atomic-free scatter
__global__ __launch_bounds__(256) void scatter_kernel(const int* __restrict__ ei,
                                                      const int* __restrict__ row_start,
                                                      const unsigned short* __restrict__ cnt,
                                                      const unsigned short* __restrict__ lrank,
                                                      int* __restrict__ csr) {
    int i = blockIdx.x * 256 + threadIdx.x;
    if (i < N_EDGES) {
        int b = i / EPB;
        int s = ei[i];
        int d = ei[N_EDGES + i];
        int pos = row_start[d] + (int)cnt[b * N_NODES + d] + (int)lrank[i];
        csr[pos] = s;
    }
}

// ---------------- mean aggregation: LDS-staged indices, 4-deep gather ILP ----------

__device__ __forceinline__ void f4add(float4& a, const float4& v) {
    a.x += v.x; a.y += v.y; a.z += v.z; a.w += v.w;
}

__global__ __launch_bounds__(128) void aggregate_kernel(const float4* __restrict__ x4,
                                                        const int* __restrict__ row_start,
                                                        const int* __restrict__ csr,
                                                        float4* __restrict__ agg4) {
    __shared__ int idx[256];
    __shared__ float4 red[4][32];
    const int node = blockIdx.x;
    const int lane = threadIdx.x & 31;
    const int slot = threadIdx.x >> 5;
    const int start = row_start[node];
    const int end = row_start[node + 1];

    float4 a0 = {0,0,0,0}, a1 = {0,0,0,0}, a2 = {0,0,0,0}, a3 = {0,0,0,0};
    for (int cs = start; cs < end; cs += 256) {
        int m = min(256, end - cs);
        if ((int)threadIdx.x < m) idx[threadIdx.x] = csr[cs + threadIdx.x];
        if ((int)threadIdx.x + 128 < m) idx[threadIdx.x + 128] = csr[cs + threadIdx.x + 128];
        __syncthreads();
        int j = slot;
        for (; j + 12 < m; j += 16) {
            int s0 = idx[j], s1 = idx[j + 4], s2 = idx[j + 8], s3 = idx[j + 12];
            float4 v0 = x4[s0 * 32 + lane];
            float4 v1 = x4[s1 * 32 + lane];
            float4 v2 = x4[s2 * 32 + lane];
            float4 v3 = x4[s3 * 32 + lane];
            f4add(a0, v0); f4add(a1, v1); f4add(a2, v2); f4add(a3, v3);
        }
        for (; j < m; j += 4) {
            float4 v = x4[idx[j] * 32 + lane];
            f4add(a0, v);
        }
        __syncthreads();
    }
    f4add(a0, a1); f4add(a2, a3); f4add(a0, a2);
    red[slot][lane] = a0;
    __syncthreads();
    if (slot == 0) {
        float4 a = red[0][lane], b = red[1][lane], c = red[2][lane], d = red[3][lane];
        int cntE = end - start;
        float inv = (cntE > 0) ? 1.0f / (float)cntE : 0.0f;
        float4 o;
        o.x = ((a.x + b.x) + (c.x + d.x)) * inv;
        o.y = ((a.y + b.y) + (c.y + d.y)) * inv;
        o.z = ((a.z + b.z) + (c.z + d.z)) * inv;
        o.w = ((a.w + b.w) + (c.w + d.w)) * inv;
        agg4[node * 32 + lane] = o;
    }
}

// ---------------- SAGE linear + residual ----------------

__global__ __launch_bounds__(128) void lin_kernel(const float* __restrict__ x,
                                                  const float* __restrict__ agg,
                                                  const float* __restrict__ Wl,
                                                  const float* __restrict__ bl,
                                                  const float* __restrict__ Wr,
                                                  float* __restrict__ out) {
    __shared__ float4 xs[8][32];
    __shared__ float4 as[8][32];
    float* xsf = (float*)xs;
    float* asf = (float*)as;
    const int f = threadIdx.x;
    const int n0 = blockIdx.x * 8;

    for (int n = 0; n < 8; ++n) {
        xsf[n * D + f] = x[(n0 + n) * D + f];
        asf[n * D + f] = agg[(n0 + n) * D + f];
    }
    __syncthreads();

    float bias = bl[f];
    float acc[8];
#pragma unroll
    for (int n = 0; n < 8; ++n) acc[n] = bias;

    const float4* wl4 = (const float4*)(Wl + f * D);
    const float4* wr4 = (const float4*)(Wr + f * D);
    for (int kk = 0; kk < 32; ++kk) {
        float4 wl = wl4[kk];
        float4 wr = wr4[kk];
#pragma unroll
        for (int n = 0; n < 8; ++n) {
            float4 a = as[n][kk];
            float4 xv = xs[n][kk];
            acc[n] += a.x * wl.x + a.y * wl.y + a.z * wl.z + a.w * wl.w;
            acc[n] += xv.x * wr.x + xv.y * wr.y + xv.z * wr.z + xv.w * wr.w;
        }
    }

    for (int n = 0; n < 8; ++n) {
        out[(n0 + n) * D + f] = xsf[n * D + f] + acc[n];
    }
}

extern "C" void kernel_launch(void* const* d_in, const int* in_sizes, int n_in,
                              void* d_out, int out_size, void* d_ws, size_t ws_size,
                              hipStream_t stream) {
    const float* x  = (const float*)d_in[0];
    const int*   ei = (const int*)d_in[1];     // [2, E] int32
    const float* Wl = (const float*)d_in[2];
    const float* bl = (const float*)d_in[3];
    const float* Wr = (const float*)d_in[4];
    float* out = (float*)d_out;

    // workspace layout (16B-aligned segments)
    unsigned long long* flags = (unsigned long long*)d_ws;              // 64 ULL
    int* row_start = (int*)(flags + 64);                                // 10016 ints
    unsigned short* cnt   = (unsigned short*)(row_start + 10016);       // NB*N_NODES
    unsigned short* lrank = cnt + (size_t)NB * N_NODES;                 // N_EDGES
    int* csr   = (int*)(lrank + N_EDGES);                               // N_EDGES
    float* agg = (float*)(csr + N_EDGES);                               // N_NODES*D

    hist_local_kernel<<<NB, 1024, 0, stream>>>(ei, lrank, cnt, flags);
    colscan_scan_kernel<<<SB, 256, 0, stream>>>(cnt, row_start, flags);
    scatter_kernel<<<(N_EDGES + 255) / 256, 256, 0, stream>>>(ei, row_start, cnt, lrank, csr);
    aggregate_kernel<<<N_NODES, 128, 0, stream>>>((const float4*)x, row_start, csr,
                                                  (float4*)agg);
    lin_kernel<<<N_NODES / 8, 128, 0, stream>>>(x, agg, Wl, bl, Wr, out);
}